// Round 8
// baseline (364.869 us; speedup 1.0000x reference)
//
#include <hip/hip_runtime.h>
#include <hip/hip_bf16.h>
#include <math.h>

typedef __attribute__((ext_vector_type(8))) short bf16x8;
typedef __attribute__((ext_vector_type(4))) float f32x4;

// Problem constants
constexpr int Bc = 2, CGc = 64, Hc = 240, Wc = 1216;
constexpr int IDXR = 4, PROP = 6;
constexpr long HW  = (long)Hc * Wc;      // 291840
constexpr long BHW = (long)Bc * HW;      // 583680

// d_out layout (floats)
constexpr long OUT0 = 0;
constexpr long OUT1 = BHW;
constexpr long OUT2 = BHW * 7;
constexpr long OUT3 = OUT2 + (long)Bc * 18 * HW;
constexpr long OUT4 = OUT3 + (long)Bc * 9 * HW;

// ---- padded NHWC bf16 guidance in ws: [b][py 0..241][px 0..1217][ic 0..63] --
// Each 128-B pixel record is stored with its 8 16-B units PRE-SWIZZLED:
// record position (j ^ (pad_px & 7)) holds data unit j. conv_lds stages the
// records linearly via global_load_lds and un-swizzles on the ds_read side.
constexpr int HP = Hc + 2, WPAD = Wc + 2;            // 242 x 1218
constexpr long APXB   = (long)HP * WPAD;
constexpr long A_TOT  = (long)Bc * APXB * 128;       // 75.5 MB
constexpr long WOFF   = A_TOT;
constexpr long WS_NEED = WOFF + (long)9 * 32 * 128;

__device__ __forceinline__ unsigned short f2bf(float f) {
  __hip_bfloat16 h = __float2bfloat16(f);
  return __builtin_bit_cast(unsigned short, h);
}

__device__ __forceinline__ float fetch_px(const float* __restrict__ img, int y, int x) {
  return (y >= 0 && y < Hc && x >= 0 && x < Wc) ? img[(long)y * Wc + x] : 0.f;
}

__device__ __forceinline__ float bilin(const float* __restrict__ img, float y, float x) {
  float y0f = floorf(y), x0f = floorf(x);
  int y0 = (int)y0f, x0 = (int)x0f;
  float wy = y - y0f, wx = x - x0f;
  float v00 = fetch_px(img, y0,     x0);
  float v01 = fetch_px(img, y0,     x0 + 1);
  float v10 = fetch_px(img, y0 + 1, x0);
  float v11 = fetch_px(img, y0 + 1, x0 + 1);
  float top = v00 + wx * (v01 - v00);
  float bot = v10 + wx * (v11 - v10);
  return top + wy * (bot - top);
}

// ---------------- NCHW f32 -> padded NHWC bf16 (tiled transpose) -------------
// Output records unit-swizzled: position (j ^ (px&7)) <- data unit j.
__global__ __launch_bounds__(256) void nhwc_kernel(
    const float* __restrict__ g, char* __restrict__ ws) {
  __shared__ __align__(16) char tileb[64 * 132];
  const int tid = threadIdx.x;
  const int x0 = blockIdx.x * 64;
  const int y  = blockIdx.y;
  const int bz = blockIdx.z;
  const float* gb = g + (long)bz * CGc * HW + (long)y * Wc + x0;
  const int px = tid & 63, wv = tid >> 6;
#pragma unroll
  for (int k = 0; k < 16; ++k) {
    int ic = k * 4 + wv;
    float v = gb[(long)ic * HW + px];
    *reinterpret_cast<unsigned short*>(tileb + px * 132 + ic * 2) = f2bf(v);
  }
  __syncthreads();
  const int opx = tid >> 2, q = tid & 3;
  unsigned int u[8];
#pragma unroll
  for (int j = 0; j < 8; ++j)
    u[j] = *reinterpret_cast<unsigned int*>(tileb + opx * 132 + q * 32 + j * 4);
  const int s = (1 + opx) & 7;   // pad_px = x0+1+opx, x0 % 64 == 0
  char* rec = ws + ((long)(bz * HP + y + 1) * WPAD + x0 + 1 + opx) * 128;
  *reinterpret_cast<uint4*>(rec + (((2 * q)     ^ s) << 4)) = make_uint4(u[0], u[1], u[2], u[3]);
  *reinterpret_cast<uint4*>(rec + (((2 * q + 1) ^ s) << 4)) = make_uint4(u[4], u[5], u[6], u[7]);
}

// ---------------- zero the pad border (zeros are swizzle-invariant) ----------
__global__ __launch_bounds__(256) void border_kernel(char* __restrict__ ws) {
  constexpr int NB = 2 * WPAD + 2 * (HP - 2);
  long i = (long)blockIdx.x * 256 + threadIdx.x;
  if (i >= (long)Bc * NB) return;
  int bz = (int)(i / NB);
  int r  = (int)(i - (long)bz * NB);
  int py, px;
  if (r < WPAD)            { py = 0;      px = r; }
  else if (r < 2 * WPAD)   { py = HP - 1; px = r - WPAD; }
  else { int qq = r - 2 * WPAD; py = 1 + (qq >> 1); px = (qq & 1) ? (WPAD - 1) : 0; }
  char* p = ws + ((long)(bz * HP + py) * WPAD + px) * 128;
  uint4 z = make_uint4(0, 0, 0, 0);
#pragma unroll
  for (int j = 0; j < 8; ++j) reinterpret_cast<uint4*>(p)[j] = z;
}

// ---------------- W: OIHW f32 -> [tap9][oc32][ic64] bf16 ---------------------
__global__ __launch_bounds__(256) void wconv_kernel(
    const float* __restrict__ w, char* __restrict__ ws) {
  char* wd = ws + WOFF;
  for (int idx = threadIdx.x; idx < 24 * 64 * 9; idx += 256) {
    int oc = idx / 576, r = idx - oc * 576;
    int ic = r / 9, tap = r - ic * 9;
    *reinterpret_cast<unsigned short*>(wd + tap * 4096 + oc * 128 + ic * 2) = f2bf(w[idx]);
  }
  for (int idx = threadIdx.x; idx < 8 * 64 * 9; idx += 256) {
    int oc = 24 + idx / 576, r = idx % 576;
    int ic = r / 9, tap = r % 9;
    *reinterpret_cast<unsigned short*>(wd + tap * 4096 + oc * 128 + ic * 2) = 0;
  }
}

// ---------------- LDS-staged MFMA conv (global_load_lds staging) -------------
constexpr int CTILE_BYTES = 6 * 66 * 128;   // 50688
constexpr int CUNITS = CTILE_BYTES / 16;    // 3168

__device__ __forceinline__ void stage_unit(const char* __restrict__ Abase,
                                           char* smemA, int u) {
  int pxl = u >> 3, j = u & 7;
  int r = pxl / 66, col = pxl - r * 66;
  const char* src = Abase + ((long)r * WPAD + col) * 128 + (j << 4);
  __builtin_amdgcn_global_load_lds(
      (const __attribute__((address_space(1))) unsigned int*)(const void*)src,
      (__attribute__((address_space(3))) unsigned int*)(void*)(smemA + u * 16),
      16, 0, 0);
}

__global__ __launch_bounds__(256) void conv_lds_kernel(
    const char* __restrict__ ws, const float* __restrict__ bias,
    float* __restrict__ out) {
  __shared__ __align__(16) char smemA[CTILE_BYTES];
  const int tid  = threadIdx.x;
  const int lane = tid & 63, wv = tid >> 6;
  const int lrow = lane & 15, lgrp = lane >> 4;
  const int x0 = blockIdx.x * 64;
  const int y0 = blockIdx.y * 4;
  const int bz = blockIdx.z;

  // ---- stage tile: pre-swizzled global records -> linear LDS copy ----
  const char* Abase = ws + ((long)(bz * HP + y0) * WPAD + x0) * 128;
#pragma unroll
  for (int it = 0; it < 12; ++it) stage_unit(Abase, smemA, it * 256 + tid);
  {
    int u = 12 * 256 + tid;
    if (u < CUNITS) stage_unit(Abase, smemA, u);
  }
  __syncthreads();

  const char* Wb = ws + WOFF + (long)lrow * 128 + lgrp * 16;

  f32x4 acc[4][2];
#pragma unroll
  for (int h = 0; h < 4; ++h)
#pragma unroll
    for (int nt = 0; nt < 2; ++nt) acc[h][nt] = (f32x4){0.f, 0.f, 0.f, 0.f};

#pragma unroll
  for (int tap = 0; tap < 9; ++tap) {
    const int dy = tap / 3, dx = tap - dy * 3;
    const char* Wt = Wb + tap * 4096;
#pragma unroll
    for (int ks = 0; ks < 2; ++ks) {
      bf16x8 wf0 = *reinterpret_cast<const bf16x8*>(Wt + ks * 64);
      bf16x8 wf1 = *reinterpret_cast<const bf16x8*>(Wt + 2048 + ks * 64);
#pragma unroll
      for (int h = 0; h < 4; ++h) {
        const int colc = lrow + dx + h * 16;
        int abyte = ((wv + dy) * 66 + colc) * 128 +
                    ((((ks << 2) + lgrp) ^ (colc & 7)) << 4);
        bf16x8 af = *reinterpret_cast<const bf16x8*>(smemA + abyte);
        acc[h][0] = __builtin_amdgcn_mfma_f32_16x16x32_bf16(af, wf0, acc[h][0], 0, 0, 0);
        acc[h][1] = __builtin_amdgcn_mfma_f32_16x16x32_bf16(af, wf1, acc[h][1], 0, 0, 0);
      }
    }
  }

  const int y = y0 + wv;
#pragma unroll
  for (int h = 0; h < 4; ++h) {
    const int xx = x0 + h * 16 + lgrp * 4;
#pragma unroll
    for (int nt = 0; nt < 2; ++nt) {
      int oc = nt * 16 + lrow;
      if (oc >= 24) continue;
      float bv = bias[oc];
      long dst;
      if (oc < 16) {
        int n = oc >> 1, cd = oc & 1;
        int mm = (n < IDXR) ? n : n + 1;
        dst = OUT2 + (long)(bz * 18 + 2 * mm + cd) * HW;
      } else {
        int i2 = oc - 16;
        int mm = (i2 < IDXR) ? i2 : i2 + 1;
        dst = OUT3 + (long)(bz * 9 + mm) * HW;
      }
      f32x4 v = acc[h][nt];
      float4 st = make_float4(v[0] + bv, v[1] + bv, v[2] + bv, v[3] + bv);
      *reinterpret_cast<float4*>(&out[dst + (long)y * Wc + xx]) = st;
    }
  }
}

// ---------------- fused prep + prop step 0 -----------------------------------
// Step 0 gathers only from initial_disp (a pure input), so no inter-block
// dependency: prep state stays in registers for the first propagation.
__global__ __launch_bounds__(256) void prep_prop0_kernel(
    const float* __restrict__ conf, const float* __restrict__ scale_p,
    const float* __restrict__ occm, const float* __restrict__ initd,
    float* __restrict__ out) {
  long p = (long)blockIdx.x * 256 + threadIdx.x;
  if (p >= BHW) return;
  int b = (int)(p / HW);
  long rem = p - (long)b * HW;
  int y = (int)(rem / Wc);
  int x = (int)(rem - (long)y * Wc);

  const float inv_scale = 1.f / (scale_p[0] + 1e-8f);
  const float* confb = conf + (long)b * HW;
  float* off  = out + OUT2 + (long)b * 18 * HW + rem;
  float* affp = out + OUT3 + (long)b * 9  * HW + rem;

  float affr[9], oyr[9], oxr[9];
  float asum = 0.f;
#pragma unroll
  for (int m = 0; m < 8; m++) {
    int n = (m < IDXR) ? m : m + 1;
    float oy  = off[(long)(2 * n) * HW];
    float ox  = off[(long)(2 * n + 1) * HW];
    float raw = affp[(long)n * HW];
    float avv = tanhf(raw) * inv_scale;
    float cs  = bilin(confb, (float)y + oy, (float)x + ox);
    affr[n] = avv * cs;
    oyr[n] = oy; oxr[n] = ox;
    asum += fabsf(affr[n]);
  }
  float s = fmaxf(asum + 1e-5f, 1.0f);
  float inv_s = 1.f / s;
  float total = 0.f;
#pragma unroll
  for (int m = 0; m < 8; m++) {
    int n = (m < IDXR) ? m : m + 1;
    affr[n] *= inv_s; total += affr[n];
  }
  affr[IDXR] = 1.f - total;
  oyr[IDXR] = 0.f; oxr[IDXR] = 0.f;
#pragma unroll
  for (int n = 0; n < 9; n++) affp[(long)n * HW] = affr[n];
  off[(long)(2 * IDXR) * HW]     = 0.f;
  off[(long)(2 * IDXR + 1) * HW] = 0.f;
  if (p == 0) out[OUT4] = scale_p[0];

  // ---- propagation step 0 (from initial_disp) ----
  const float* db = initd + (long)b * HW;
  float acc = 0.f;
#pragma unroll
  for (int k = 0; k < 9; k++) {
    float sy = (float)(y + k / 3 - 1) + oyr[k];
    float sx = (float)(x + k % 3 - 1) + oxr[k];
    acc = fmaf(affr[k], bilin(db, sy, sx), acc);
  }
  acc = fmaxf(acc, 0.f);
  float o = occm[p];
  float res = (1.f - o) * acc + o * db[rem];
  out[OUT1 + p] = res;
}

// ---------------- propagation steps 1..5, 2 px/thread ------------------------
__global__ __launch_bounds__(256) void prop2_kernel(
    const float* __restrict__ dispPrev,
    const float* __restrict__ occ, const float* __restrict__ initd,
    float* __restrict__ out, int t) {
  long p0 = ((long)blockIdx.x * 256 + threadIdx.x) * 2;
  if (p0 >= BHW) return;
  int b = (int)(p0 / HW);
  long rem = p0 - (long)b * HW;
  const float* off  = out + OUT2 + (long)b * 18 * HW + rem;
  const float* affp = out + OUT3 + (long)b * 9  * HW + rem;
  const float* db   = dispPrev + (long)b * HW;

  float av[2][9], oyv[2][9], oxv[2][9];
#pragma unroll
  for (int k = 0; k < 9; k++) {
    float2 a2 = *reinterpret_cast<const float2*>(&affp[(long)k * HW]);
    float2 y2 = *reinterpret_cast<const float2*>(&off[(long)(2 * k) * HW]);
    float2 x2 = *reinterpret_cast<const float2*>(&off[(long)(2 * k + 1) * HW]);
    av[0][k] = a2.x;  av[1][k] = a2.y;
    oyv[0][k] = y2.x; oyv[1][k] = y2.y;
    oxv[0][k] = x2.x; oxv[1][k] = x2.y;
  }
  float2 oc2 = *reinterpret_cast<const float2*>(&occ[p0]);
  float2 in2 = *reinterpret_cast<const float2*>(&initd[p0]);

  float res[2];
#pragma unroll
  for (int j = 0; j < 2; j++) {
    long remj = rem + j;
    int y = (int)(remj / Wc);
    int x = (int)(remj - (long)y * Wc);
    float acc = 0.f;
#pragma unroll
    for (int k = 0; k < 9; k++) {
      float sy = (float)(y + k / 3 - 1) + oyv[j][k];
      float sx = (float)(x + k % 3 - 1) + oxv[j][k];
      acc = fmaf(av[j][k], bilin(db, sy, sx), acc);
    }
    acc = fmaxf(acc, 0.f);
    float o  = (j == 0) ? oc2.x : oc2.y;
    float iv = (j == 0) ? in2.x : in2.y;
    res[j] = (1.f - o) * acc + o * iv;
  }
  *reinterpret_cast<float2*>(&out[OUT1 + (long)t * BHW + p0]) = make_float2(res[0], res[1]);
  if (t == PROP - 1)
    *reinterpret_cast<float2*>(&out[OUT0 + p0]) = make_float2(res[0], res[1]);
}

// ================= legacy fallback path (ws too small) =======================
constexpr int TY = 8, TX = 32;
constexpr int AR = TY + 2, AC = TX + 2;
constexpr int A_BYTES = AR * AC * CGc * 2;
constexpr int W_BYTES = 9 * 32 * 32 * 2;

__global__ __launch_bounds__(256) void conv_mfma_kernel(
    const float* __restrict__ g, const float* __restrict__ wsrc,
    const float* __restrict__ bias, float* __restrict__ out) {
  __shared__ __align__(16) char smemA[A_BYTES];
  __shared__ __align__(16) char smemW[W_BYTES];
  const int tid = threadIdx.x;
  const int x0 = blockIdx.x * TX;
  const int y0 = blockIdx.y * TY;
  const int bz = blockIdx.z;
  const float* gb = g + (long)bz * CGc * HW;
  for (int w = tid; w < AR * AC * 32; w += 256) {
    int c  = w % AC;
    int t2 = w / AC;
    int icp = t2 & 31;
    int r   = t2 >> 5;
    int y = y0 + r - 1, x = x0 + c - 1;
    float v0 = 0.f, v1 = 0.f;
    if (y >= 0 && y < Hc && x >= 0 && x < Wc) {
      const float* p = gb + (long)(2 * icp) * HW + (long)y * Wc + x;
      v0 = p[0]; v1 = p[HW];
    }
    unsigned int pk = (unsigned int)f2bf(v0) | ((unsigned int)f2bf(v1) << 16);
    int byte = (r * AC + c) * 128 + icp * 4;
    byte ^= (c & 7) << 4;
    *reinterpret_cast<unsigned int*>(smemA + byte) = pk;
  }
  auto stageW = [&](int hs) {
    for (int idx = tid; idx < 24 * 32 * 9; idx += 256) {
      int oc  = idx / 288;
      int r1  = idx - oc * 288;
      int icl = r1 / 9;
      int tap = r1 - icl * 9;
      float f = wsrc[idx + 288 * (oc + hs)];
      int byte = (tap * 32 + oc) * 64 + icl * 2;
      byte ^= (oc & 7) << 4;
      *reinterpret_cast<unsigned short*>(smemW + byte) = f2bf(f);
    }
  };
  stageW(0);
  __syncthreads();
  const int wid  = tid >> 6;
  const int lane = tid & 63;
  const int lrow = lane & 15;
  const int lgrp = lane >> 4;
  f32x4 acc[4][2];
#pragma unroll
  for (int m = 0; m < 4; m++)
#pragma unroll
    for (int nt = 0; nt < 2; nt++) acc[m][nt] = (f32x4){0.f, 0.f, 0.f, 0.f};
  for (int ks = 0; ks < 2; ++ks) {
    if (ks) { __syncthreads(); stageW(1); __syncthreads(); }
#pragma unroll
    for (int tap = 0; tap < 9; ++tap) {
      const int dy = tap / 3, dx = tap - dy * 3;
      int bb = (tap * 32 + lrow) * 64 + lgrp * 16;
      int bbyte0 = bb ^ ((lrow & 7) << 4);
      int bbyte1 = (bb + 16 * 64) ^ ((lrow & 7) << 4);
      bf16x8 bf0 = *reinterpret_cast<const bf16x8*>(smemW + bbyte0);
      bf16x8 bf1 = *reinterpret_cast<const bf16x8*>(smemW + bbyte1);
#pragma unroll
      for (int dr = 0; dr < 2; ++dr) {
        const int rin = 2 * wid + dr + dy;
#pragma unroll
        for (int h = 0; h < 2; ++h) {
          const int cin = h * 16 + lrow + dx;
          int abyte = ((rin * AC + cin) * 128 + ks * 64 + lgrp * 16) ^ ((cin & 7) << 4);
          bf16x8 af = *reinterpret_cast<const bf16x8*>(smemA + abyte);
          acc[dr * 2 + h][0] = __builtin_amdgcn_mfma_f32_16x16x32_bf16(af, bf0, acc[dr * 2 + h][0], 0, 0, 0);
          acc[dr * 2 + h][1] = __builtin_amdgcn_mfma_f32_16x16x32_bf16(af, bf1, acc[dr * 2 + h][1], 0, 0, 0);
        }
      }
    }
  }
#pragma unroll
  for (int dr = 0; dr < 2; ++dr) {
    const int yy = y0 + 2 * wid + dr;
#pragma unroll
    for (int h = 0; h < 2; ++h) {
      const int xx = x0 + h * 16 + lgrp * 4;
#pragma unroll
      for (int nt = 0; nt < 2; ++nt) {
        int oc = nt * 16 + lrow;
        if (oc >= 24) continue;
        float bv = bias[oc];
        long dst;
        if (oc < 16) {
          int n = oc >> 1, cd = oc & 1;
          int mm = (n < IDXR) ? n : n + 1;
          dst = OUT2 + (long)(bz * 18 + 2 * mm + cd) * HW;
        } else {
          int i2 = oc - 16;
          int mm = (i2 < IDXR) ? i2 : i2 + 1;
          dst = OUT3 + (long)(bz * 9 + mm) * HW;
        }
        f32x4 v = acc[dr * 2 + h][nt];
        float4 st = make_float4(v[0] + bv, v[1] + bv, v[2] + bv, v[3] + bv);
        *reinterpret_cast<float4*>(&out[dst + (long)yy * Wc + xx]) = st;
      }
    }
  }
}

__global__ __launch_bounds__(256) void prep_kernel(
    const float* __restrict__ conf, const float* __restrict__ scale_p,
    float* __restrict__ out) {
  long p = (long)blockIdx.x * 256 + threadIdx.x;
  if (p >= BHW) return;
  int b = (int)(p / HW);
  long rem = p - (long)b * HW;
  int y = (int)(rem / Wc);
  int x = (int)(rem - (long)y * Wc);
  const float inv_scale = 1.f / (scale_p[0] + 1e-8f);
  const float* confb = conf + (long)b * HW;
  float* off  = out + OUT2 + (long)b * 18 * HW + rem;
  float* affp = out + OUT3 + (long)b * 9  * HW + rem;
  float a[8];
  float asum = 0.f;
#pragma unroll
  for (int m = 0; m < 8; m++) {
    int n = (m < IDXR) ? m : m + 1;
    float oy  = off[(long)(2 * n) * HW];
    float ox  = off[(long)(2 * n + 1) * HW];
    float raw = affp[(long)n * HW];
    float av  = tanhf(raw) * inv_scale;
    float cs  = bilin(confb, (float)y + oy, (float)x + ox);
    a[m] = av * cs;
    asum += fabsf(a[m]);
  }
  float s = fmaxf(asum + 1e-5f, 1.0f);
  float inv_s = 1.f / s;
  float total = 0.f;
#pragma unroll
  for (int m = 0; m < 8; m++) { a[m] *= inv_s; total += a[m]; }
  float aref = 1.f - total;
#pragma unroll
  for (int m = 0; m < 8; m++) {
    int n = (m < IDXR) ? m : m + 1;
    affp[(long)n * HW] = a[m];
  }
  affp[(long)IDXR * HW] = aref;
  off[(long)(2 * IDXR) * HW]     = 0.f;
  off[(long)(2 * IDXR + 1) * HW] = 0.f;
  if (p == 0) out[OUT4] = scale_p[0];
}

__global__ __launch_bounds__(256) void prop_kernel(
    const float* __restrict__ dispPrev,
    const float* __restrict__ occ, const float* __restrict__ initd,
    float* __restrict__ out, int t) {
  long p = (long)blockIdx.x * 256 + threadIdx.x;
  if (p >= BHW) return;
  int b = (int)(p / HW);
  long rem = p - (long)b * HW;
  int y = (int)(rem / Wc);
  int x = (int)(rem - (long)y * Wc);
  const float* off  = out + OUT2 + (long)b * 18 * HW + rem;
  const float* affp = out + OUT3 + (long)b * 9  * HW + rem;
  const float* db   = dispPrev + (long)b * HW;
  float acc = 0.f;
#pragma unroll
  for (int k = 0; k < 9; k++) {
    float oy = off[(long)(2 * k) * HW];
    float ox = off[(long)(2 * k + 1) * HW];
    float av = affp[(long)k * HW];
    float sy = (float)(y + k / 3 - 1) + oy;
    float sx = (float)(x + k % 3 - 1) + ox;
    acc = fmaf(av, bilin(db, sy, sx), acc);
  }
  acc = fmaxf(acc, 0.f);
  float o = occ[p];
  float res = (1.f - o) * acc + o * initd[p];
  out[OUT1 + (long)t * BHW + p] = res;
  if (t == PROP - 1) out[OUT0 + p] = res;
}

extern "C" void kernel_launch(void* const* d_in, const int* in_sizes, int n_in,
                              void* d_out, int out_size, void* d_ws, size_t ws_size,
                              hipStream_t stream) {
  const float* initd = (const float*)d_in[0];
  const float* occ   = (const float*)d_in[1];
  const float* conf  = (const float*)d_in[2];
  const float* guid  = (const float*)d_in[3];
  const float* cw    = (const float*)d_in[4];
  const float* cb    = (const float*)d_in[5];
  const float* csc   = (const float*)d_in[6];
  float* out = (float*)d_out;
  int nblk  = (int)((BHW + 255) / 256);      // 2280
  int nblk2 = (int)((BHW / 2 + 255) / 256);  // 1140

  if (ws_size >= (size_t)WS_NEED) {
    char* ws = (char*)d_ws;
    nhwc_kernel<<<dim3(Wc / 64, Hc, Bc), 256, 0, stream>>>(guid, ws);
    border_kernel<<<(Bc * (2 * WPAD + 2 * (HP - 2)) + 255) / 256, 256, 0, stream>>>(ws);
    wconv_kernel<<<1, 256, 0, stream>>>(cw, ws);
    conv_lds_kernel<<<dim3(Wc / 64, Hc / 4, Bc), 256, 0, stream>>>(ws, cb, out);

    prep_prop0_kernel<<<nblk, 256, 0, stream>>>(conf, csc, occ, initd, out);
    for (int t = 1; t < PROP; t++) {
      const float* dp = out + OUT1 + (long)(t - 1) * BHW;
      prop2_kernel<<<nblk2, 256, 0, stream>>>(dp, occ, initd, out, t);
    }
  } else {
    conv_mfma_kernel<<<dim3(Wc / TX, Hc / TY, Bc), 256, 0, stream>>>(guid, cw, cb, out);
    prep_kernel<<<nblk, 256, 0, stream>>>(conf, csc, out);
    for (int t = 0; t < PROP; t++) {
      const float* dp = (t == 0) ? initd : (out + OUT1 + (long)(t - 1) * BHW);
      prop_kernel<<<nblk, 256, 0, stream>>>(dp, occ, initd, out, t);
    }
  }
}

// Round 9
// 359.736 us; speedup vs baseline: 1.0143x; 1.0143x over previous
//
#include <hip/hip_runtime.h>
#include <hip/hip_bf16.h>
#include <math.h>

typedef __attribute__((ext_vector_type(8))) short bf16x8;
typedef __attribute__((ext_vector_type(4))) float f32x4;

// Problem constants
constexpr int Bc = 2, CGc = 64, Hc = 240, Wc = 1216;
constexpr int IDXR = 4, PROP = 6;
constexpr long HW  = (long)Hc * Wc;      // 291840
constexpr long BHW = (long)Bc * HW;      // 583680

// d_out layout (floats)
constexpr long OUT0 = 0;
constexpr long OUT1 = BHW;
constexpr long OUT2 = BHW * 7;
constexpr long OUT3 = OUT2 + (long)Bc * 18 * HW;
constexpr long OUT4 = OUT3 + (long)Bc * 9 * HW;

// ---- padded NHWC bf16 guidance in ws: [b][py 0..241][px 0..1217][ic 0..63] --
constexpr int HP = Hc + 2, WPAD = Wc + 2;            // 242 x 1218
constexpr long APXB   = (long)HP * WPAD;
constexpr long A_TOT  = (long)Bc * APXB * 128;       // 75.5 MB
constexpr long WOFF   = A_TOT;
constexpr long WS_NEED = WOFF + (long)9 * 32 * 128;

__device__ __forceinline__ unsigned short f2bf(float f) {
  __hip_bfloat16 h = __float2bfloat16(f);
  return __builtin_bit_cast(unsigned short, h);
}

__device__ __forceinline__ float fetch_px(const float* __restrict__ img, int y, int x) {
  return (y >= 0 && y < Hc && x >= 0 && x < Wc) ? img[(long)y * Wc + x] : 0.f;
}

__device__ __forceinline__ float bilin(const float* __restrict__ img, float y, float x) {
  float y0f = floorf(y), x0f = floorf(x);
  int y0 = (int)y0f, x0 = (int)x0f;
  float wy = y - y0f, wx = x - x0f;
  float v00 = fetch_px(img, y0,     x0);
  float v01 = fetch_px(img, y0,     x0 + 1);
  float v10 = fetch_px(img, y0 + 1, x0);
  float v11 = fetch_px(img, y0 + 1, x0 + 1);
  float top = v00 + wx * (v01 - v00);
  float bot = v10 + wx * (v11 - v10);
  return top + wy * (bot - top);
}

// ---------------- NCHW f32 -> padded NHWC bf16 (tiled transpose) -------------
// (round-6 proven version: linear records, fully coalesced 2KB wave writes)
__global__ __launch_bounds__(256) void nhwc_kernel(
    const float* __restrict__ g, char* __restrict__ ws) {
  __shared__ __align__(16) char tileb[64 * 132];
  const int tid = threadIdx.x;
  const int x0 = blockIdx.x * 64;
  const int y  = blockIdx.y;
  const int bz = blockIdx.z;
  const float* gb = g + (long)bz * CGc * HW + (long)y * Wc + x0;
  const int px = tid & 63, wv = tid >> 6;
#pragma unroll
  for (int k = 0; k < 16; ++k) {
    int ic = k * 4 + wv;
    float v = gb[(long)ic * HW + px];
    *reinterpret_cast<unsigned short*>(tileb + px * 132 + ic * 2) = f2bf(v);
  }
  __syncthreads();
  const int opx = tid >> 2, q = tid & 3;
  unsigned int u[8];
#pragma unroll
  for (int j = 0; j < 8; ++j)
    u[j] = *reinterpret_cast<unsigned int*>(tileb + opx * 132 + q * 32 + j * 4);
  char* dst = ws + ((long)(bz * HP + y + 1) * WPAD + x0 + 1 + opx) * 128 + q * 32;
  reinterpret_cast<uint4*>(dst)[0] = make_uint4(u[0], u[1], u[2], u[3]);
  reinterpret_cast<uint4*>(dst)[1] = make_uint4(u[4], u[5], u[6], u[7]);
}

// ---------------- zero the pad border ---------------------------------------
__global__ __launch_bounds__(256) void border_kernel(char* __restrict__ ws) {
  constexpr int NB = 2 * WPAD + 2 * (HP - 2);
  long i = (long)blockIdx.x * 256 + threadIdx.x;
  if (i >= (long)Bc * NB) return;
  int bz = (int)(i / NB);
  int r  = (int)(i - (long)bz * NB);
  int py, px;
  if (r < WPAD)            { py = 0;      px = r; }
  else if (r < 2 * WPAD)   { py = HP - 1; px = r - WPAD; }
  else { int qq = r - 2 * WPAD; py = 1 + (qq >> 1); px = (qq & 1) ? (WPAD - 1) : 0; }
  char* p = ws + ((long)(bz * HP + py) * WPAD + px) * 128;
  uint4 z = make_uint4(0, 0, 0, 0);
#pragma unroll
  for (int j = 0; j < 8; ++j) reinterpret_cast<uint4*>(p)[j] = z;
}

// ---------------- W: OIHW f32 -> [tap9][oc32][ic64] bf16 (72 blocks) ---------
__global__ __launch_bounds__(256) void wconv_kernel(
    const float* __restrict__ w, char* __restrict__ ws) {
  char* wd = ws + WOFF;
  int idx = blockIdx.x * 256 + threadIdx.x;
  if (idx < 24 * 64 * 9) {
    int oc = idx / 576, r = idx - oc * 576;
    int ic = r / 9, tap = r - ic * 9;
    *reinterpret_cast<unsigned short*>(wd + tap * 4096 + oc * 128 + ic * 2) = f2bf(w[idx]);
  } else if (idx < 32 * 64 * 9) {
    int i2 = idx - 24 * 64 * 9;
    int oc = 24 + i2 / 576, r = i2 % 576;
    int ic = r / 9, tap = r % 9;
    *reinterpret_cast<unsigned short*>(wd + tap * 4096 + oc * 128 + ic * 2) = 0;
  }
}

// ---------------- LDS-staged MFMA conv (round-6 proven staging) --------------
constexpr int CTILE_BYTES = 6 * 66 * 128;   // 50688
constexpr int CUNITS = CTILE_BYTES / 16;    // 3168

__global__ __launch_bounds__(256) void conv_lds_kernel(
    const char* __restrict__ ws, const float* __restrict__ bias,
    float* __restrict__ out) {
  __shared__ __align__(16) char smemA[CTILE_BYTES];
  const int tid  = threadIdx.x;
  const int lane = tid & 63, wv = tid >> 6;
  const int lrow = lane & 15, lgrp = lane >> 4;
  const int x0 = blockIdx.x * 64;
  const int y0 = blockIdx.y * 4;
  const int bz = blockIdx.z;

  // ---- stage tile: coalesced global dwordx4 -> swizzled ds_write_b128 ----
  const char* Abase = ws + ((long)(bz * HP + y0) * WPAD + x0) * 128;
#pragma unroll
  for (int it = 0; it < 13; ++it) {
    int u = it * 256 + tid;
    if (u < CUNITS) {
      int pxl = u >> 3, j = u & 7;
      int r = pxl / 66, col = pxl - r * 66;
      uint4 v = *reinterpret_cast<const uint4*>(
          Abase + ((long)r * WPAD + col) * 128 + j * 16);
      int ldsb = pxl * 128 + ((j ^ (col & 7)) << 4);
      *reinterpret_cast<uint4*>(smemA + ldsb) = v;
    }
  }
  __syncthreads();

  const char* Wb = ws + WOFF + (long)lrow * 128 + lgrp * 16;

  f32x4 acc[4][2];
#pragma unroll
  for (int h = 0; h < 4; ++h)
#pragma unroll
    for (int nt = 0; nt < 2; ++nt) acc[h][nt] = (f32x4){0.f, 0.f, 0.f, 0.f};

#pragma unroll
  for (int tap = 0; tap < 9; ++tap) {
    const int dy = tap / 3, dx = tap - dy * 3;
    const char* Wt = Wb + tap * 4096;
#pragma unroll
    for (int ks = 0; ks < 2; ++ks) {
      bf16x8 wf0 = *reinterpret_cast<const bf16x8*>(Wt + ks * 64);
      bf16x8 wf1 = *reinterpret_cast<const bf16x8*>(Wt + 2048 + ks * 64);
#pragma unroll
      for (int h = 0; h < 4; ++h) {
        const int colc = lrow + dx + h * 16;
        int abyte = ((wv + dy) * 66 + colc) * 128 +
                    ((((ks << 2) + lgrp) ^ (colc & 7)) << 4);
        bf16x8 af = *reinterpret_cast<const bf16x8*>(smemA + abyte);
        acc[h][0] = __builtin_amdgcn_mfma_f32_16x16x32_bf16(af, wf0, acc[h][0], 0, 0, 0);
        acc[h][1] = __builtin_amdgcn_mfma_f32_16x16x32_bf16(af, wf1, acc[h][1], 0, 0, 0);
      }
    }
  }

  const int y = y0 + wv;
#pragma unroll
  for (int h = 0; h < 4; ++h) {
    const int xx = x0 + h * 16 + lgrp * 4;
#pragma unroll
    for (int nt = 0; nt < 2; ++nt) {
      int oc = nt * 16 + lrow;
      if (oc >= 24) continue;
      float bv = bias[oc];
      long dst;
      if (oc < 16) {
        int n = oc >> 1, cd = oc & 1;
        int mm = (n < IDXR) ? n : n + 1;
        dst = OUT2 + (long)(bz * 18 + 2 * mm + cd) * HW;
      } else {
        int i2 = oc - 16;
        int mm = (i2 < IDXR) ? i2 : i2 + 1;
        dst = OUT3 + (long)(bz * 9 + mm) * HW;
      }
      f32x4 v = acc[h][nt];
      float4 st = make_float4(v[0] + bv, v[1] + bv, v[2] + bv, v[3] + bv);
      *reinterpret_cast<float4*>(&out[dst + (long)y * Wc + xx]) = st;
    }
  }
}

// ---------------- fused prep + prop step 0 -----------------------------------
__global__ __launch_bounds__(256) void prep_prop0_kernel(
    const float* __restrict__ conf, const float* __restrict__ scale_p,
    const float* __restrict__ occm, const float* __restrict__ initd,
    float* __restrict__ out) {
  long p = (long)blockIdx.x * 256 + threadIdx.x;
  if (p >= BHW) return;
  int b = (int)(p / HW);
  long rem = p - (long)b * HW;
  int y = (int)(rem / Wc);
  int x = (int)(rem - (long)y * Wc);

  const float inv_scale = 1.f / (scale_p[0] + 1e-8f);
  const float* confb = conf + (long)b * HW;
  float* off  = out + OUT2 + (long)b * 18 * HW + rem;
  float* affp = out + OUT3 + (long)b * 9  * HW + rem;

  float affr[9], oyr[9], oxr[9];
  float asum = 0.f;
#pragma unroll
  for (int m = 0; m < 8; m++) {
    int n = (m < IDXR) ? m : m + 1;
    float oy  = off[(long)(2 * n) * HW];
    float ox  = off[(long)(2 * n + 1) * HW];
    float raw = affp[(long)n * HW];
    float avv = tanhf(raw) * inv_scale;
    float cs  = bilin(confb, (float)y + oy, (float)x + ox);
    affr[n] = avv * cs;
    oyr[n] = oy; oxr[n] = ox;
    asum += fabsf(affr[n]);
  }
  float s = fmaxf(asum + 1e-5f, 1.0f);
  float inv_s = 1.f / s;
  float total = 0.f;
#pragma unroll
  for (int m = 0; m < 8; m++) {
    int n = (m < IDXR) ? m : m + 1;
    affr[n] *= inv_s; total += affr[n];
  }
  affr[IDXR] = 1.f - total;
  oyr[IDXR] = 0.f; oxr[IDXR] = 0.f;
#pragma unroll
  for (int n = 0; n < 9; n++) affp[(long)n * HW] = affr[n];
  off[(long)(2 * IDXR) * HW]     = 0.f;
  off[(long)(2 * IDXR + 1) * HW] = 0.f;
  if (p == 0) out[OUT4] = scale_p[0];

  // ---- propagation step 0 (from initial_disp) ----
  const float* db = initd + (long)b * HW;
  float acc = 0.f;
#pragma unroll
  for (int k = 0; k < 9; k++) {
    float sy = (float)(y + k / 3 - 1) + oyr[k];
    float sx = (float)(x + k % 3 - 1) + oxr[k];
    acc = fmaf(affr[k], bilin(db, sy, sx), acc);
  }
  acc = fmaxf(acc, 0.f);
  float o = occm[p];
  float res = (1.f - o) * acc + o * db[rem];
  out[OUT1 + p] = res;
}

// ---------------- propagation steps 1..5, 2 px/thread ------------------------
__global__ __launch_bounds__(256) void prop2_kernel(
    const float* __restrict__ dispPrev,
    const float* __restrict__ occ, const float* __restrict__ initd,
    float* __restrict__ out, int t) {
  long p0 = ((long)blockIdx.x * 256 + threadIdx.x) * 2;
  if (p0 >= BHW) return;
  int b = (int)(p0 / HW);
  long rem = p0 - (long)b * HW;
  const float* off  = out + OUT2 + (long)b * 18 * HW + rem;
  const float* affp = out + OUT3 + (long)b * 9  * HW + rem;
  const float* db   = dispPrev + (long)b * HW;

  float av[2][9], oyv[2][9], oxv[2][9];
#pragma unroll
  for (int k = 0; k < 9; k++) {
    float2 a2 = *reinterpret_cast<const float2*>(&affp[(long)k * HW]);
    float2 y2 = *reinterpret_cast<const float2*>(&off[(long)(2 * k) * HW]);
    float2 x2 = *reinterpret_cast<const float2*>(&off[(long)(2 * k + 1) * HW]);
    av[0][k] = a2.x;  av[1][k] = a2.y;
    oyv[0][k] = y2.x; oyv[1][k] = y2.y;
    oxv[0][k] = x2.x; oxv[1][k] = x2.y;
  }
  float2 oc2 = *reinterpret_cast<const float2*>(&occ[p0]);
  float2 in2 = *reinterpret_cast<const float2*>(&initd[p0]);

  float res[2];
#pragma unroll
  for (int j = 0; j < 2; j++) {
    long remj = rem + j;
    int y = (int)(remj / Wc);
    int x = (int)(remj - (long)y * Wc);
    float acc = 0.f;
#pragma unroll
    for (int k = 0; k < 9; k++) {
      float sy = (float)(y + k / 3 - 1) + oyv[j][k];
      float sx = (float)(x + k % 3 - 1) + oxv[j][k];
      acc = fmaf(av[j][k], bilin(db, sy, sx), acc);
    }
    acc = fmaxf(acc, 0.f);
    float o  = (j == 0) ? oc2.x : oc2.y;
    float iv = (j == 0) ? in2.x : in2.y;
    res[j] = (1.f - o) * acc + o * iv;
  }
  *reinterpret_cast<float2*>(&out[OUT1 + (long)t * BHW + p0]) = make_float2(res[0], res[1]);
  if (t == PROP - 1)
    *reinterpret_cast<float2*>(&out[OUT0 + p0]) = make_float2(res[0], res[1]);
}

// ================= legacy fallback path (ws too small) =======================
constexpr int TY = 8, TX = 32;
constexpr int AR = TY + 2, AC = TX + 2;
constexpr int A_BYTES = AR * AC * CGc * 2;
constexpr int W_BYTES = 9 * 32 * 32 * 2;

__global__ __launch_bounds__(256) void conv_mfma_kernel(
    const float* __restrict__ g, const float* __restrict__ wsrc,
    const float* __restrict__ bias, float* __restrict__ out) {
  __shared__ __align__(16) char smemA[A_BYTES];
  __shared__ __align__(16) char smemW[W_BYTES];
  const int tid = threadIdx.x;
  const int x0 = blockIdx.x * TX;
  const int y0 = blockIdx.y * TY;
  const int bz = blockIdx.z;
  const float* gb = g + (long)bz * CGc * HW;
  for (int w = tid; w < AR * AC * 32; w += 256) {
    int c  = w % AC;
    int t2 = w / AC;
    int icp = t2 & 31;
    int r   = t2 >> 5;
    int y = y0 + r - 1, x = x0 + c - 1;
    float v0 = 0.f, v1 = 0.f;
    if (y >= 0 && y < Hc && x >= 0 && x < Wc) {
      const float* p = gb + (long)(2 * icp) * HW + (long)y * Wc + x;
      v0 = p[0]; v1 = p[HW];
    }
    unsigned int pk = (unsigned int)f2bf(v0) | ((unsigned int)f2bf(v1) << 16);
    int byte = (r * AC + c) * 128 + icp * 4;
    byte ^= (c & 7) << 4;
    *reinterpret_cast<unsigned int*>(smemA + byte) = pk;
  }
  auto stageW = [&](int hs) {
    for (int idx = tid; idx < 24 * 32 * 9; idx += 256) {
      int oc  = idx / 288;
      int r1  = idx - oc * 288;
      int icl = r1 / 9;
      int tap = r1 - icl * 9;
      float f = wsrc[idx + 288 * (oc + hs)];
      int byte = (tap * 32 + oc) * 64 + icl * 2;
      byte ^= (oc & 7) << 4;
      *reinterpret_cast<unsigned short*>(smemW + byte) = f2bf(f);
    }
  };
  stageW(0);
  __syncthreads();
  const int wid  = tid >> 6;
  const int lane = tid & 63;
  const int lrow = lane & 15;
  const int lgrp = lane >> 4;
  f32x4 acc[4][2];
#pragma unroll
  for (int m = 0; m < 4; m++)
#pragma unroll
    for (int nt = 0; nt < 2; nt++) acc[m][nt] = (f32x4){0.f, 0.f, 0.f, 0.f};
  for (int ks = 0; ks < 2; ++ks) {
    if (ks) { __syncthreads(); stageW(1); __syncthreads(); }
#pragma unroll
    for (int tap = 0; tap < 9; ++tap) {
      const int dy = tap / 3, dx = tap - dy * 3;
      int bb = (tap * 32 + lrow) * 64 + lgrp * 16;
      int bbyte0 = bb ^ ((lrow & 7) << 4);
      int bbyte1 = (bb + 16 * 64) ^ ((lrow & 7) << 4);
      bf16x8 bf0 = *reinterpret_cast<const bf16x8*>(smemW + bbyte0);
      bf16x8 bf1 = *reinterpret_cast<const bf16x8*>(smemW + bbyte1);
#pragma unroll
      for (int dr = 0; dr < 2; ++dr) {
        const int rin = 2 * wid + dr + dy;
#pragma unroll
        for (int h = 0; h < 2; ++h) {
          const int cin = h * 16 + lrow + dx;
          int abyte = ((rin * AC + cin) * 128 + ks * 64 + lgrp * 16) ^ ((cin & 7) << 4);
          bf16x8 af = *reinterpret_cast<const bf16x8*>(smemA + abyte);
          acc[dr * 2 + h][0] = __builtin_amdgcn_mfma_f32_16x16x32_bf16(af, bf0, acc[dr * 2 + h][0], 0, 0, 0);
          acc[dr * 2 + h][1] = __builtin_amdgcn_mfma_f32_16x16x32_bf16(af, bf1, acc[dr * 2 + h][1], 0, 0, 0);
        }
      }
    }
  }
#pragma unroll
  for (int dr = 0; dr < 2; ++dr) {
    const int yy = y0 + 2 * wid + dr;
#pragma unroll
    for (int h = 0; h < 2; ++h) {
      const int xx = x0 + h * 16 + lgrp * 4;
#pragma unroll
      for (int nt = 0; nt < 2; ++nt) {
        int oc = nt * 16 + lrow;
        if (oc >= 24) continue;
        float bv = bias[oc];
        long dst;
        if (oc < 16) {
          int n = oc >> 1, cd = oc & 1;
          int mm = (n < IDXR) ? n : n + 1;
          dst = OUT2 + (long)(bz * 18 + 2 * mm + cd) * HW;
        } else {
          int i2 = oc - 16;
          int mm = (i2 < IDXR) ? i2 : i2 + 1;
          dst = OUT3 + (long)(bz * 9 + mm) * HW;
        }
        f32x4 v = acc[dr * 2 + h][nt];
        float4 st = make_float4(v[0] + bv, v[1] + bv, v[2] + bv, v[3] + bv);
        *reinterpret_cast<float4*>(&out[dst + (long)yy * Wc + xx]) = st;
      }
    }
  }
}

__global__ __launch_bounds__(256) void prep_kernel(
    const float* __restrict__ conf, const float* __restrict__ scale_p,
    float* __restrict__ out) {
  long p = (long)blockIdx.x * 256 + threadIdx.x;
  if (p >= BHW) return;
  int b = (int)(p / HW);
  long rem = p - (long)b * HW;
  int y = (int)(rem / Wc);
  int x = (int)(rem - (long)y * Wc);
  const float inv_scale = 1.f / (scale_p[0] + 1e-8f);
  const float* confb = conf + (long)b * HW;
  float* off  = out + OUT2 + (long)b * 18 * HW + rem;
  float* affp = out + OUT3 + (long)b * 9  * HW + rem;
  float a[8];
  float asum = 0.f;
#pragma unroll
  for (int m = 0; m < 8; m++) {
    int n = (m < IDXR) ? m : m + 1;
    float oy  = off[(long)(2 * n) * HW];
    float ox  = off[(long)(2 * n + 1) * HW];
    float raw = affp[(long)n * HW];
    float av  = tanhf(raw) * inv_scale;
    float cs  = bilin(confb, (float)y + oy, (float)x + ox);
    a[m] = av * cs;
    asum += fabsf(a[m]);
  }
  float s = fmaxf(asum + 1e-5f, 1.0f);
  float inv_s = 1.f / s;
  float total = 0.f;
#pragma unroll
  for (int m = 0; m < 8; m++) { a[m] *= inv_s; total += a[m]; }
  float aref = 1.f - total;
#pragma unroll
  for (int m = 0; m < 8; m++) {
    int n = (m < IDXR) ? m : m + 1;
    affp[(long)n * HW] = a[m];
  }
  affp[(long)IDXR * HW] = aref;
  off[(long)(2 * IDXR) * HW]     = 0.f;
  off[(long)(2 * IDXR + 1) * HW] = 0.f;
  if (p == 0) out[OUT4] = scale_p[0];
}

__global__ __launch_bounds__(256) void prop_kernel(
    const float* __restrict__ dispPrev,
    const float* __restrict__ occ, const float* __restrict__ initd,
    float* __restrict__ out, int t) {
  long p = (long)blockIdx.x * 256 + threadIdx.x;
  if (p >= BHW) return;
  int b = (int)(p / HW);
  long rem = p - (long)b * HW;
  int y = (int)(rem / Wc);
  int x = (int)(rem - (long)y * Wc);
  const float* off  = out + OUT2 + (long)b * 18 * HW + rem;
  const float* affp = out + OUT3 + (long)b * 9  * HW + rem;
  const float* db   = dispPrev + (long)b * HW;
  float acc = 0.f;
#pragma unroll
  for (int k = 0; k < 9; k++) {
    float oy = off[(long)(2 * k) * HW];
    float ox = off[(long)(2 * k + 1) * HW];
    float av = affp[(long)k * HW];
    float sy = (float)(y + k / 3 - 1) + oy;
    float sx = (float)(x + k % 3 - 1) + ox;
    acc = fmaf(av, bilin(db, sy, sx), acc);
  }
  acc = fmaxf(acc, 0.f);
  float o = occ[p];
  float res = (1.f - o) * acc + o * initd[p];
  out[OUT1 + (long)t * BHW + p] = res;
  if (t == PROP - 1) out[OUT0 + p] = res;
}

extern "C" void kernel_launch(void* const* d_in, const int* in_sizes, int n_in,
                              void* d_out, int out_size, void* d_ws, size_t ws_size,
                              hipStream_t stream) {
  const float* initd = (const float*)d_in[0];
  const float* occ   = (const float*)d_in[1];
  const float* conf  = (const float*)d_in[2];
  const float* guid  = (const float*)d_in[3];
  const float* cw    = (const float*)d_in[4];
  const float* cb    = (const float*)d_in[5];
  const float* csc   = (const float*)d_in[6];
  float* out = (float*)d_out;
  int nblk  = (int)((BHW + 255) / 256);      // 2280
  int nblk2 = (int)((BHW / 2 + 255) / 256);  // 1140

  if (ws_size >= (size_t)WS_NEED) {
    char* ws = (char*)d_ws;
    nhwc_kernel<<<dim3(Wc / 64, Hc, Bc), 256, 0, stream>>>(guid, ws);
    border_kernel<<<(Bc * (2 * WPAD + 2 * (HP - 2)) + 255) / 256, 256, 0, stream>>>(ws);
    wconv_kernel<<<72, 256, 0, stream>>>(cw, ws);
    conv_lds_kernel<<<dim3(Wc / 64, Hc / 4, Bc), 256, 0, stream>>>(ws, cb, out);

    prep_prop0_kernel<<<nblk, 256, 0, stream>>>(conf, csc, occ, initd, out);
    for (int t = 1; t < PROP; t++) {
      const float* dp = out + OUT1 + (long)(t - 1) * BHW;
      prop2_kernel<<<nblk2, 256, 0, stream>>>(dp, occ, initd, out, t);
    }
  } else {
    conv_mfma_kernel<<<dim3(Wc / TX, Hc / TY, Bc), 256, 0, stream>>>(guid, cw, cb, out);
    prep_kernel<<<nblk, 256, 0, stream>>>(conf, csc, out);
    for (int t = 0; t < PROP; t++) {
      const float* dp = (t == 0) ? initd : (out + OUT1 + (long)(t - 1) * BHW);
      prop_kernel<<<nblk, 256, 0, stream>>>(dp, occ, initd, out, t);
    }
  }
}

// Round 10
// 273.494 us; speedup vs baseline: 1.3341x; 1.3153x over previous
//
#include <hip/hip_runtime.h>
#include <hip/hip_bf16.h>
#include <math.h>

typedef __attribute__((ext_vector_type(8))) short bf16x8;
typedef __attribute__((ext_vector_type(4))) float f32x4;

// Problem constants
constexpr int Bc = 2, CGc = 64, Hc = 240, Wc = 1216;
constexpr int IDXR = 4, PROP = 6;
constexpr long HW  = (long)Hc * Wc;      // 291840
constexpr long BHW = (long)Bc * HW;      // 583680

// d_out layout (floats)
constexpr long OUT0 = 0;
constexpr long OUT1 = BHW;
constexpr long OUT2 = BHW * 7;
constexpr long OUT3 = OUT2 + (long)Bc * 18 * HW;
constexpr long OUT4 = OUT3 + (long)Bc * 9 * HW;

// ---- padded NHWC bf16 guidance in ws: [b][py 0..241][px 0..1217][ic 0..63] --
constexpr int HP = Hc + 2, WPAD = Wc + 2;            // 242 x 1218
constexpr long APXB   = (long)HP * WPAD;
constexpr long A_TOT  = (long)Bc * APXB * 128;       // 75.5 MB
constexpr long WOFF   = A_TOT;
constexpr long WS_NEED = WOFF + (long)9 * 32 * 128;

__device__ __forceinline__ unsigned short f2bf(float f) {
  __hip_bfloat16 h = __float2bfloat16(f);
  return __builtin_bit_cast(unsigned short, h);
}

__device__ __forceinline__ float fetch_px(const float* __restrict__ img, int y, int x) {
  return (y >= 0 && y < Hc && x >= 0 && x < Wc) ? img[(long)y * Wc + x] : 0.f;
}

__device__ __forceinline__ float bilin(const float* __restrict__ img, float y, float x) {
  float y0f = floorf(y), x0f = floorf(x);
  int y0 = (int)y0f, x0 = (int)x0f;
  float wy = y - y0f, wx = x - x0f;
  float v00 = fetch_px(img, y0,     x0);
  float v01 = fetch_px(img, y0,     x0 + 1);
  float v10 = fetch_px(img, y0 + 1, x0);
  float v11 = fetch_px(img, y0 + 1, x0 + 1);
  float top = v00 + wx * (v01 - v00);
  float bot = v10 + wx * (v11 - v10);
  return top + wy * (bot - top);
}

// ---------------- NCHW f32 -> padded NHWC bf16 (tiled transpose) -------------
__global__ __launch_bounds__(256) void nhwc_kernel(
    const float* __restrict__ g, char* __restrict__ ws) {
  __shared__ __align__(16) char tileb[64 * 132];
  const int tid = threadIdx.x;
  const int x0 = blockIdx.x * 64;
  const int y  = blockIdx.y;
  const int bz = blockIdx.z;
  const float* gb = g + (long)bz * CGc * HW + (long)y * Wc + x0;
  const int px = tid & 63, wv = tid >> 6;
#pragma unroll
  for (int k = 0; k < 16; ++k) {
    int ic = k * 4 + wv;
    float v = gb[(long)ic * HW + px];
    *reinterpret_cast<unsigned short*>(tileb + px * 132 + ic * 2) = f2bf(v);
  }
  __syncthreads();
  const int opx = tid >> 2, q = tid & 3;
  unsigned int u[8];
#pragma unroll
  for (int j = 0; j < 8; ++j)
    u[j] = *reinterpret_cast<unsigned int*>(tileb + opx * 132 + q * 32 + j * 4);
  char* dst = ws + ((long)(bz * HP + y + 1) * WPAD + x0 + 1 + opx) * 128 + q * 32;
  reinterpret_cast<uint4*>(dst)[0] = make_uint4(u[0], u[1], u[2], u[3]);
  reinterpret_cast<uint4*>(dst)[1] = make_uint4(u[4], u[5], u[6], u[7]);
}

// ---------------- zero the pad border ---------------------------------------
__global__ __launch_bounds__(256) void border_kernel(char* __restrict__ ws) {
  constexpr int NB = 2 * WPAD + 2 * (HP - 2);
  long i = (long)blockIdx.x * 256 + threadIdx.x;
  if (i >= (long)Bc * NB) return;
  int bz = (int)(i / NB);
  int r  = (int)(i - (long)bz * NB);
  int py, px;
  if (r < WPAD)            { py = 0;      px = r; }
  else if (r < 2 * WPAD)   { py = HP - 1; px = r - WPAD; }
  else { int qq = r - 2 * WPAD; py = 1 + (qq >> 1); px = (qq & 1) ? (WPAD - 1) : 0; }
  char* p = ws + ((long)(bz * HP + py) * WPAD + px) * 128;
  uint4 z = make_uint4(0, 0, 0, 0);
#pragma unroll
  for (int j = 0; j < 8; ++j) reinterpret_cast<uint4*>(p)[j] = z;
}

// ---------------- W: OIHW f32 -> [tap9][oc32][ic64] bf16 (72 blocks) ---------
__global__ __launch_bounds__(256) void wconv_kernel(
    const float* __restrict__ w, char* __restrict__ ws) {
  char* wd = ws + WOFF;
  int idx = blockIdx.x * 256 + threadIdx.x;
  if (idx < 24 * 64 * 9) {
    int oc = idx / 576, r = idx - oc * 576;
    int ic = r / 9, tap = r - ic * 9;
    *reinterpret_cast<unsigned short*>(wd + tap * 4096 + oc * 128 + ic * 2) = f2bf(w[idx]);
  } else if (idx < 32 * 64 * 9) {
    int i2 = idx - 24 * 64 * 9;
    int oc = 24 + i2 / 576, r = i2 % 576;
    int ic = r / 9, tap = r % 9;
    *reinterpret_cast<unsigned short*>(wd + tap * 4096 + oc * 128 + ic * 2) = 0;
  }
}

// ---------------- LDS-staged MFMA conv (round-6 proven staging) --------------
constexpr int CTILE_BYTES = 6 * 66 * 128;   // 50688
constexpr int CUNITS = CTILE_BYTES / 16;    // 3168

__global__ __launch_bounds__(256) void conv_lds_kernel(
    const char* __restrict__ ws, const float* __restrict__ bias,
    float* __restrict__ out) {
  __shared__ __align__(16) char smemA[CTILE_BYTES];
  const int tid  = threadIdx.x;
  const int lane = tid & 63, wv = tid >> 6;
  const int lrow = lane & 15, lgrp = lane >> 4;
  const int x0 = blockIdx.x * 64;
  const int y0 = blockIdx.y * 4;
  const int bz = blockIdx.z;

  const char* Abase = ws + ((long)(bz * HP + y0) * WPAD + x0) * 128;
#pragma unroll
  for (int it = 0; it < 13; ++it) {
    int u = it * 256 + tid;
    if (u < CUNITS) {
      int pxl = u >> 3, j = u & 7;
      int r = pxl / 66, col = pxl - r * 66;
      uint4 v = *reinterpret_cast<const uint4*>(
          Abase + ((long)r * WPAD + col) * 128 + j * 16);
      int ldsb = pxl * 128 + ((j ^ (col & 7)) << 4);
      *reinterpret_cast<uint4*>(smemA + ldsb) = v;
    }
  }
  __syncthreads();

  const char* Wb = ws + WOFF + (long)lrow * 128 + lgrp * 16;

  f32x4 acc[4][2];
#pragma unroll
  for (int h = 0; h < 4; ++h)
#pragma unroll
    for (int nt = 0; nt < 2; ++nt) acc[h][nt] = (f32x4){0.f, 0.f, 0.f, 0.f};

#pragma unroll
  for (int tap = 0; tap < 9; ++tap) {
    const int dy = tap / 3, dx = tap - dy * 3;
    const char* Wt = Wb + tap * 4096;
#pragma unroll
    for (int ks = 0; ks < 2; ++ks) {
      bf16x8 wf0 = *reinterpret_cast<const bf16x8*>(Wt + ks * 64);
      bf16x8 wf1 = *reinterpret_cast<const bf16x8*>(Wt + 2048 + ks * 64);
#pragma unroll
      for (int h = 0; h < 4; ++h) {
        const int colc = lrow + dx + h * 16;
        int abyte = ((wv + dy) * 66 + colc) * 128 +
                    ((((ks << 2) + lgrp) ^ (colc & 7)) << 4);
        bf16x8 af = *reinterpret_cast<const bf16x8*>(smemA + abyte);
        acc[h][0] = __builtin_amdgcn_mfma_f32_16x16x32_bf16(af, wf0, acc[h][0], 0, 0, 0);
        acc[h][1] = __builtin_amdgcn_mfma_f32_16x16x32_bf16(af, wf1, acc[h][1], 0, 0, 0);
      }
    }
  }

  const int y = y0 + wv;
#pragma unroll
  for (int h = 0; h < 4; ++h) {
    const int xx = x0 + h * 16 + lgrp * 4;
#pragma unroll
    for (int nt = 0; nt < 2; ++nt) {
      int oc = nt * 16 + lrow;
      if (oc >= 24) continue;
      float bv = bias[oc];
      long dst;
      if (oc < 16) {
        int n = oc >> 1, cd = oc & 1;
        int mm = (n < IDXR) ? n : n + 1;
        dst = OUT2 + (long)(bz * 18 + 2 * mm + cd) * HW;
      } else {
        int i2 = oc - 16;
        int mm = (i2 < IDXR) ? i2 : i2 + 1;
        dst = OUT3 + (long)(bz * 9 + mm) * HW;
      }
      f32x4 v = acc[h][nt];
      float4 st = make_float4(v[0] + bv, v[1] + bv, v[2] + bv, v[3] + bv);
      *reinterpret_cast<float4*>(&out[dst + (long)y * Wc + xx]) = st;
    }
  }
}

// ---------------- fused prep + prop step 0 (1 px/thread) ---------------------
__global__ __launch_bounds__(256) void prep_prop0_kernel(
    const float* __restrict__ conf, const float* __restrict__ scale_p,
    const float* __restrict__ occm, const float* __restrict__ initd,
    float* __restrict__ out) {
  long p = (long)blockIdx.x * 256 + threadIdx.x;
  if (p >= BHW) return;
  int b = (int)(p / HW);
  long rem = p - (long)b * HW;
  int y = (int)(rem / Wc);
  int x = (int)(rem - (long)y * Wc);

  const float inv_scale = 1.f / (scale_p[0] + 1e-8f);
  const float* confb = conf + (long)b * HW;
  float* off  = out + OUT2 + (long)b * 18 * HW + rem;
  float* affp = out + OUT3 + (long)b * 9  * HW + rem;

  float affr[9], oyr[9], oxr[9];
  float asum = 0.f;
#pragma unroll
  for (int m = 0; m < 8; m++) {
    int n = (m < IDXR) ? m : m + 1;
    float oy  = off[(long)(2 * n) * HW];
    float ox  = off[(long)(2 * n + 1) * HW];
    float raw = affp[(long)n * HW];
    float avv = tanhf(raw) * inv_scale;
    float cs  = bilin(confb, (float)y + oy, (float)x + ox);
    affr[n] = avv * cs;
    oyr[n] = oy; oxr[n] = ox;
    asum += fabsf(affr[n]);
  }
  float s = fmaxf(asum + 1e-5f, 1.0f);
  float inv_s = 1.f / s;
  float total = 0.f;
#pragma unroll
  for (int m = 0; m < 8; m++) {
    int n = (m < IDXR) ? m : m + 1;
    affr[n] *= inv_s; total += affr[n];
  }
  affr[IDXR] = 1.f - total;
  oyr[IDXR] = 0.f; oxr[IDXR] = 0.f;
#pragma unroll
  for (int n = 0; n < 9; n++) affp[(long)n * HW] = affr[n];
  off[(long)(2 * IDXR) * HW]     = 0.f;
  off[(long)(2 * IDXR + 1) * HW] = 0.f;
  if (p == 0) out[OUT4] = scale_p[0];

  // ---- propagation step 0 (from initial_disp) ----
  const float* db = initd + (long)b * HW;
  float acc = 0.f;
#pragma unroll
  for (int k = 0; k < 9; k++) {
    float sy = (float)(y + k / 3 - 1) + oyr[k];
    float sx = (float)(x + k % 3 - 1) + oxr[k];
    acc = fmaf(affr[k], bilin(db, sy, sx), acc);
  }
  acc = fmaxf(acc, 0.f);
  float o = occm[p];
  float res = (1.f - o) * acc + o * db[rem];
  out[OUT1 + p] = res;
}

// ---------------- one propagation step (1 px/thread, round-6 proven) ---------
__global__ __launch_bounds__(256) void prop_kernel(
    const float* __restrict__ dispPrev,
    const float* __restrict__ occ, const float* __restrict__ initd,
    float* __restrict__ out, int t) {
  long p = (long)blockIdx.x * 256 + threadIdx.x;
  if (p >= BHW) return;
  int b = (int)(p / HW);
  long rem = p - (long)b * HW;
  int y = (int)(rem / Wc);
  int x = (int)(rem - (long)y * Wc);

  const float* off  = out + OUT2 + (long)b * 18 * HW + rem;
  const float* affp = out + OUT3 + (long)b * 9  * HW + rem;
  const float* db   = dispPrev + (long)b * HW;

  float acc = 0.f;
#pragma unroll
  for (int k = 0; k < 9; k++) {
    float oy = off[(long)(2 * k) * HW];
    float ox = off[(long)(2 * k + 1) * HW];
    float av = affp[(long)k * HW];
    float sy = (float)(y + k / 3 - 1) + oy;
    float sx = (float)(x + k % 3 - 1) + ox;
    acc = fmaf(av, bilin(db, sy, sx), acc);
  }
  acc = fmaxf(acc, 0.f);
  float o = occ[p];
  float res = (1.f - o) * acc + o * initd[p];
  out[OUT1 + (long)t * BHW + p] = res;
  if (t == PROP - 1) out[OUT0 + p] = res;
}

// ================= legacy fallback path (ws too small) =======================
constexpr int TY = 8, TX = 32;
constexpr int AR = TY + 2, AC = TX + 2;
constexpr int A_BYTES = AR * AC * CGc * 2;
constexpr int W_BYTES = 9 * 32 * 32 * 2;

__global__ __launch_bounds__(256) void conv_mfma_kernel(
    const float* __restrict__ g, const float* __restrict__ wsrc,
    const float* __restrict__ bias, float* __restrict__ out) {
  __shared__ __align__(16) char smemA[A_BYTES];
  __shared__ __align__(16) char smemW[W_BYTES];
  const int tid = threadIdx.x;
  const int x0 = blockIdx.x * TX;
  const int y0 = blockIdx.y * TY;
  const int bz = blockIdx.z;
  const float* gb = g + (long)bz * CGc * HW;
  for (int w = tid; w < AR * AC * 32; w += 256) {
    int c  = w % AC;
    int t2 = w / AC;
    int icp = t2 & 31;
    int r   = t2 >> 5;
    int y = y0 + r - 1, x = x0 + c - 1;
    float v0 = 0.f, v1 = 0.f;
    if (y >= 0 && y < Hc && x >= 0 && x < Wc) {
      const float* p = gb + (long)(2 * icp) * HW + (long)y * Wc + x;
      v0 = p[0]; v1 = p[HW];
    }
    unsigned int pk = (unsigned int)f2bf(v0) | ((unsigned int)f2bf(v1) << 16);
    int byte = (r * AC + c) * 128 + icp * 4;
    byte ^= (c & 7) << 4;
    *reinterpret_cast<unsigned int*>(smemA + byte) = pk;
  }
  auto stageW = [&](int hs) {
    for (int idx = tid; idx < 24 * 32 * 9; idx += 256) {
      int oc  = idx / 288;
      int r1  = idx - oc * 288;
      int icl = r1 / 9;
      int tap = r1 - icl * 9;
      float f = wsrc[idx + 288 * (oc + hs)];
      int byte = (tap * 32 + oc) * 64 + icl * 2;
      byte ^= (oc & 7) << 4;
      *reinterpret_cast<unsigned short*>(smemW + byte) = f2bf(f);
    }
  };
  stageW(0);
  __syncthreads();
  const int wid  = tid >> 6;
  const int lane = tid & 63;
  const int lrow = lane & 15;
  const int lgrp = lane >> 4;
  f32x4 acc[4][2];
#pragma unroll
  for (int m = 0; m < 4; m++)
#pragma unroll
    for (int nt = 0; nt < 2; nt++) acc[m][nt] = (f32x4){0.f, 0.f, 0.f, 0.f};
  for (int ks = 0; ks < 2; ++ks) {
    if (ks) { __syncthreads(); stageW(1); __syncthreads(); }
#pragma unroll
    for (int tap = 0; tap < 9; ++tap) {
      const int dy = tap / 3, dx = tap - dy * 3;
      int bb = (tap * 32 + lrow) * 64 + lgrp * 16;
      int bbyte0 = bb ^ ((lrow & 7) << 4);
      int bbyte1 = (bb + 16 * 64) ^ ((lrow & 7) << 4);
      bf16x8 bf0 = *reinterpret_cast<const bf16x8*>(smemW + bbyte0);
      bf16x8 bf1 = *reinterpret_cast<const bf16x8*>(smemW + bbyte1);
#pragma unroll
      for (int dr = 0; dr < 2; ++dr) {
        const int rin = 2 * wid + dr + dy;
#pragma unroll
        for (int h = 0; h < 2; ++h) {
          const int cin = h * 16 + lrow + dx;
          int abyte = ((rin * AC + cin) * 128 + ks * 64 + lgrp * 16) ^ ((cin & 7) << 4);
          bf16x8 af = *reinterpret_cast<const bf16x8*>(smemA + abyte);
          acc[dr * 2 + h][0] = __builtin_amdgcn_mfma_f32_16x16x32_bf16(af, bf0, acc[dr * 2 + h][0], 0, 0, 0);
          acc[dr * 2 + h][1] = __builtin_amdgcn_mfma_f32_16x16x32_bf16(af, bf1, acc[dr * 2 + h][1], 0, 0, 0);
        }
      }
    }
  }
#pragma unroll
  for (int dr = 0; dr < 2; ++dr) {
    const int yy = y0 + 2 * wid + dr;
#pragma unroll
    for (int h = 0; h < 2; ++h) {
      const int xx = x0 + h * 16 + lgrp * 4;
#pragma unroll
      for (int nt = 0; nt < 2; ++nt) {
        int oc = nt * 16 + lrow;
        if (oc >= 24) continue;
        float bv = bias[oc];
        long dst;
        if (oc < 16) {
          int n = oc >> 1, cd = oc & 1;
          int mm = (n < IDXR) ? n : n + 1;
          dst = OUT2 + (long)(bz * 18 + 2 * mm + cd) * HW;
        } else {
          int i2 = oc - 16;
          int mm = (i2 < IDXR) ? i2 : i2 + 1;
          dst = OUT3 + (long)(bz * 9 + mm) * HW;
        }
        f32x4 v = acc[dr * 2 + h][nt];
        float4 st = make_float4(v[0] + bv, v[1] + bv, v[2] + bv, v[3] + bv);
        *reinterpret_cast<float4*>(&out[dst + (long)yy * Wc + xx]) = st;
      }
    }
  }
}

__global__ __launch_bounds__(256) void prep_kernel(
    const float* __restrict__ conf, const float* __restrict__ scale_p,
    float* __restrict__ out) {
  long p = (long)blockIdx.x * 256 + threadIdx.x;
  if (p >= BHW) return;
  int b = (int)(p / HW);
  long rem = p - (long)b * HW;
  int y = (int)(rem / Wc);
  int x = (int)(rem - (long)y * Wc);
  const float inv_scale = 1.f / (scale_p[0] + 1e-8f);
  const float* confb = conf + (long)b * HW;
  float* off  = out + OUT2 + (long)b * 18 * HW + rem;
  float* affp = out + OUT3 + (long)b * 9  * HW + rem;
  float a[8];
  float asum = 0.f;
#pragma unroll
  for (int m = 0; m < 8; m++) {
    int n = (m < IDXR) ? m : m + 1;
    float oy  = off[(long)(2 * n) * HW];
    float ox  = off[(long)(2 * n + 1) * HW];
    float raw = affp[(long)n * HW];
    float av  = tanhf(raw) * inv_scale;
    float cs  = bilin(confb, (float)y + oy, (float)x + ox);
    a[m] = av * cs;
    asum += fabsf(a[m]);
  }
  float s = fmaxf(asum + 1e-5f, 1.0f);
  float inv_s = 1.f / s;
  float total = 0.f;
#pragma unroll
  for (int m = 0; m < 8; m++) { a[m] *= inv_s; total += a[m]; }
  float aref = 1.f - total;
#pragma unroll
  for (int m = 0; m < 8; m++) {
    int n = (m < IDXR) ? m : m + 1;
    affp[(long)n * HW] = a[m];
  }
  affp[(long)IDXR * HW] = aref;
  off[(long)(2 * IDXR) * HW]     = 0.f;
  off[(long)(2 * IDXR + 1) * HW] = 0.f;
  if (p == 0) out[OUT4] = scale_p[0];
}

extern "C" void kernel_launch(void* const* d_in, const int* in_sizes, int n_in,
                              void* d_out, int out_size, void* d_ws, size_t ws_size,
                              hipStream_t stream) {
  const float* initd = (const float*)d_in[0];
  const float* occ   = (const float*)d_in[1];
  const float* conf  = (const float*)d_in[2];
  const float* guid  = (const float*)d_in[3];
  const float* cw    = (const float*)d_in[4];
  const float* cb    = (const float*)d_in[5];
  const float* csc   = (const float*)d_in[6];
  float* out = (float*)d_out;
  int nblk = (int)((BHW + 255) / 256);  // 2280

  if (ws_size >= (size_t)WS_NEED) {
    char* ws = (char*)d_ws;
    nhwc_kernel<<<dim3(Wc / 64, Hc, Bc), 256, 0, stream>>>(guid, ws);
    border_kernel<<<(Bc * (2 * WPAD + 2 * (HP - 2)) + 255) / 256, 256, 0, stream>>>(ws);
    wconv_kernel<<<72, 256, 0, stream>>>(cw, ws);
    conv_lds_kernel<<<dim3(Wc / 64, Hc / 4, Bc), 256, 0, stream>>>(ws, cb, out);

    prep_prop0_kernel<<<nblk, 256, 0, stream>>>(conf, csc, occ, initd, out);
    for (int t = 1; t < PROP; t++) {
      const float* dp = out + OUT1 + (long)(t - 1) * BHW;
      prop_kernel<<<nblk, 256, 0, stream>>>(dp, occ, initd, out, t);
    }
  } else {
    conv_mfma_kernel<<<dim3(Wc / TX, Hc / TY, Bc), 256, 0, stream>>>(guid, cw, cb, out);
    prep_kernel<<<nblk, 256, 0, stream>>>(conf, csc, out);
    for (int t = 0; t < PROP; t++) {
      const float* dp = (t == 0) ? initd : (out + OUT1 + (long)(t - 1) * BHW);
      prop_kernel<<<nblk, 256, 0, stream>>>(dp, occ, initd, out, t);
    }
  }
}